// Round 8
// baseline (51.008 us; speedup 1.0000x reference)
//
#include <hip/hip_runtime.h>

#define OUTN 400
#define THRESH 0.7f
#define BB 32
#define HH 512
#define WW 512
#define CC 3
#define BIGI 0x7FFFFFFF

#define CHUNKS_PB 32                    // chunks per batch
#define ROWS_PC   (HH / CHUNKS_PB)      // 16 rows per chunk
#define PXPB      (OUTN * OUTN)         // 160000 px per batch
#define PXB       1024                  // px per resize block

typedef float vfloat4 __attribute__((ext_vector_type(4)));

// Per-(batch,chunk) partial bounds, plain stores, no init / no global atomics.
__global__ void __launch_bounds__(256) bounds_part_kernel(
        const float* __restrict__ tensor,
        int4* __restrict__ part) {
    const int task  = blockIdx.x;            // 0..1023
    const int b     = task >> 5;
    const int chunk = task & 31;

    const float4* base = (const float4*)(tensor + (size_t)b * HH * WW
                                                + (size_t)chunk * ROWS_PC * WW);

    int minR = BIGI, maxR = -1, minC = BIGI, maxC = -1;

    // 2048 float4 per chunk, 256 threads, 8 fully-unrolled iterations
    #pragma unroll
    for (int it = 0; it < 8; ++it) {
        int p = threadIdx.x + it * 256;
        float4 v = base[p];
        int row  = p >> 7;                 // /128 float4 per row, chunk-relative
        int col0 = (p & 127) * 4;
        int mask = (v.x > THRESH ? 1 : 0) | (v.y > THRESH ? 2 : 0)
                 | (v.z > THRESH ? 4 : 0) | (v.w > THRESH ? 8 : 0);
        if (mask) {
            minR = min(minR, row);
            maxR = max(maxR, row);
            minC = min(minC, col0 + __builtin_ctz(mask));
            maxC = max(maxC, col0 + (31 - __builtin_clz(mask)));
        }
    }

    #pragma unroll
    for (int off = 32; off > 0; off >>= 1) {
        minR = min(minR, __shfl_down(minR, off));
        maxR = max(maxR, __shfl_down(maxR, off));
        minC = min(minC, __shfl_down(minC, off));
        maxC = max(maxC, __shfl_down(maxC, off));
    }

    __shared__ int s[4];
    if (threadIdx.x == 0) { s[0] = BIGI; s[1] = -1; s[2] = BIGI; s[3] = -1; }
    __syncthreads();
    if ((threadIdx.x & 63) == 0) {
        atomicMin(&s[0], minR); atomicMax(&s[1], maxR);
        atomicMin(&s[2], minC); atomicMax(&s[3], maxC);
    }
    __syncthreads();
    if (threadIdx.x == 0) {
        int4 r;
        if (s[1] >= 0) {
            r.x = s[0] + chunk * ROWS_PC;
            r.y = s[1] + chunk * ROWS_PC;
            r.z = s[2];
            r.w = s[3];
        } else {
            r.x = BIGI; r.y = -1; r.z = BIGI; r.w = -1;
        }
        part[task] = r;
    }
}

__device__ inline int4 fold_bounds(const int4* __restrict__ part, int b, int lane) {
    int4 p = part[b * CHUNKS_PB + (lane & 31)];
    #pragma unroll
    for (int off = 1; off < 32; off <<= 1) {
        p.x = min(p.x, __shfl_xor(p.x, off));
        p.y = max(p.y, __shfl_xor(p.y, off));
        p.z = min(p.z, __shfl_xor(p.z, off));
        p.w = max(p.w, __shfl_xor(p.w, off));
    }
    if (p.y < 0) { p.x = 0; p.y = HH - 1; }   // all-false mask => [0, n-1]
    if (p.w < 0) { p.z = 0; p.w = WW - 1; }
    return p;
}

// 4 consecutive px per thread; block covers 1024 consecutive px. Output store =
// 3 aligned float4 per thread. Address phase -> load phase -> blend phase.
__global__ void __launch_bounds__(256) resize_kernel(
        const float* __restrict__ img,
        const int4* __restrict__ part,
        float* __restrict__ out) {
    const int t = threadIdx.x;
    const size_t base = (size_t)blockIdx.x * PXB;
    const int b0 = (int)(base / PXPB);
    const int b1 = (int)((base + PXB - 1) / PXPB);
    const int lane = t & 63;

    int4 f0 = fold_bounds(part, b0, lane);
    int4 f1 = (b1 == b0) ? f0 : fold_bounds(part, b1, lane);
    const size_t split = (size_t)(b0 + 1) * PXPB;   // first px of batch b1

    const float* p00[4]; const float* p01[4];
    const float* p10[4]; const float* p11[4];
    float wcv[4], wrv[4];

    #pragma unroll
    for (int k = 0; k < 4; ++k) {
        size_t g   = base + (size_t)t * 4 + k;
        bool  hi   = (g >= split);
        int   b    = hi ? b1 : b0;
        int4  f    = hi ? f1 : f0;
        int   pix  = (int)(g - (size_t)b * PXPB);
        int   ocol = pix % OUTN;
        int   orow = pix / OUTN;

        const int minR = f.x, maxR = f.y, minC = f.z, maxC = f.w;

        float sizeR = (float)(maxR - minR);
        float srcR  = ((float)orow + 0.5f) * sizeR / (float)OUTN - 0.5f;
        srcR = fminf(fmaxf(srcR, 0.0f), fmaxf(sizeR - 1.0f, 0.0f));
        int   i0 = (int)floorf(srcR);
        int   i1 = min(i0 + 1, max(maxR - minR - 1, 0));
        wrv[k] = srcR - (float)i0;
        int r0 = minR + i0, r1 = minR + i1;

        float sizeC = (float)(maxC - minC);
        float srcC  = ((float)ocol + 0.5f) * sizeC / (float)OUTN - 0.5f;
        srcC = fminf(fmaxf(srcC, 0.0f), fmaxf(sizeC - 1.0f, 0.0f));
        int   j0 = (int)floorf(srcC);
        int   j1 = min(j0 + 1, max(maxC - minC - 1, 0));
        wcv[k] = srcC - (float)j0;
        int c0 = minC + j0, c1 = minC + j1;

        const float* ib = img + (size_t)b * HH * WW * CC;
        p00[k] = ib + ((size_t)r0 * WW + c0) * CC;
        p01[k] = ib + ((size_t)r0 * WW + c1) * CC;
        p10[k] = ib + ((size_t)r1 * WW + c0) * CC;
        p11[k] = ib + ((size_t)r1 * WW + c1) * CC;
    }

    // load phase: all 16 texels (48 floats) issued together
    float a00[4][3], a01[4][3], a10[4][3], a11[4][3];
    #pragma unroll
    for (int k = 0; k < 4; ++k) {
        #pragma unroll
        for (int ch = 0; ch < CC; ++ch) {
            a00[k][ch] = p00[k][ch];
            a01[k][ch] = p01[k][ch];
            a10[k][ch] = p10[k][ch];
            a11[k][ch] = p11[k][ch];
        }
    }

    // blend phase
    float res[12];
    #pragma unroll
    for (int k = 0; k < 4; ++k) {
        float wc = wcv[k], wr = wrv[k];
        float omc = 1.0f - wc, omr = 1.0f - wr;
        #pragma unroll
        for (int ch = 0; ch < CC; ++ch) {
            float top = a00[k][ch] * omc + a01[k][ch] * wc;
            float bot = a10[k][ch] * omc + a11[k][ch] * wc;
            res[k * 3 + ch] = top * omr + bot * wr;
        }
    }

    vfloat4* o = (vfloat4*)(out + base * CC) + t * 3;
    vfloat4 r0v = { res[0], res[1], res[2],  res[3] };
    vfloat4 r1v = { res[4], res[5], res[6],  res[7] };
    vfloat4 r2v = { res[8], res[9], res[10], res[11] };
    __builtin_nontemporal_store(r0v, o + 0);
    __builtin_nontemporal_store(r1v, o + 1);
    __builtin_nontemporal_store(r2v, o + 2);
}

extern "C" void kernel_launch(void* const* d_in, const int* in_sizes, int n_in,
                              void* d_out, int out_size, void* d_ws, size_t ws_size,
                              hipStream_t stream) {
    const float* image  = (const float*)d_in[0];
    const float* tensor = (const float*)d_in[1];
    float* out  = (float*)d_out;
    int4*  part = (int4*)d_ws;   // 1024 * 16 B = 16 KB

    hipLaunchKernelGGL(bounds_part_kernel, dim3(BB * CHUNKS_PB), dim3(256), 0, stream,
                       tensor, part);

    int blocks = BB * OUTN * OUTN / PXB;      // 5000
    hipLaunchKernelGGL(resize_kernel, dim3(blocks), dim3(256), 0, stream,
                       image, part, out);
}

// Round 9
// 43.798 us; speedup vs baseline: 1.1646x; 1.1646x over previous
//
#include <hip/hip_runtime.h>

#define OUTN 400
#define THRESH 0.7f
#define BB 32
#define HH 512
#define WW 512
#define CC 3
#define BIGI 0x7FFFFFFF

#define CHUNKS_PB 32                    // bounds chunks per batch
#define ROWS_PC   (HH / CHUNKS_PB)      // 16 rows per chunk
#define PXPB      (OUTN * OUTN)         // 160000 px per batch
#define TPB       320                   // resize threads per block (5 waves)
#define PXB       (TPB * 2)             // 640 px per block -> 250 blocks/batch exact
#define BLKS_PB   (PXPB / PXB)          // 250

// Per-(batch,chunk) partial bounds, plain stores, no init / no global atomics.
__global__ void __launch_bounds__(256) bounds_part_kernel(
        const float* __restrict__ tensor,
        int4* __restrict__ part) {
    const int task  = blockIdx.x;            // 0..1023
    const int b     = task >> 5;
    const int chunk = task & 31;

    const float4* base = (const float4*)(tensor + (size_t)b * HH * WW
                                                + (size_t)chunk * ROWS_PC * WW);

    int minR = BIGI, maxR = -1, minC = BIGI, maxC = -1;

    // 2048 float4 per chunk, 256 threads, 8 fully-unrolled iterations
    #pragma unroll
    for (int it = 0; it < 8; ++it) {
        int p = threadIdx.x + it * 256;
        float4 v = base[p];
        int row  = p >> 7;                 // /128 float4 per row, chunk-relative
        int col0 = (p & 127) * 4;
        int mask = (v.x > THRESH ? 1 : 0) | (v.y > THRESH ? 2 : 0)
                 | (v.z > THRESH ? 4 : 0) | (v.w > THRESH ? 8 : 0);
        if (mask) {
            minR = min(minR, row);
            maxR = max(maxR, row);
            minC = min(minC, col0 + __builtin_ctz(mask));
            maxC = max(maxC, col0 + (31 - __builtin_clz(mask)));
        }
    }

    #pragma unroll
    for (int off = 32; off > 0; off >>= 1) {
        minR = min(minR, __shfl_down(minR, off));
        maxR = max(maxR, __shfl_down(maxR, off));
        minC = min(minC, __shfl_down(minC, off));
        maxC = max(maxC, __shfl_down(maxC, off));
    }

    __shared__ int s[4];
    if (threadIdx.x == 0) { s[0] = BIGI; s[1] = -1; s[2] = BIGI; s[3] = -1; }
    __syncthreads();
    if ((threadIdx.x & 63) == 0) {
        atomicMin(&s[0], minR); atomicMax(&s[1], maxR);
        atomicMin(&s[2], minC); atomicMax(&s[3], maxC);
    }
    __syncthreads();
    if (threadIdx.x == 0) {
        int4 r;
        if (s[1] >= 0) {
            r.x = s[0] + chunk * ROWS_PC;
            r.y = s[1] + chunk * ROWS_PC;
            r.z = s[2];
            r.w = s[3];
        } else {
            r.x = BIGI; r.y = -1; r.z = BIGI; r.w = -1;
        }
        part[task] = r;
    }
}

__device__ inline int4 fold_bounds(const int4* __restrict__ part, int b, int lane) {
    int4 p = part[b * CHUNKS_PB + (lane & 31)];
    #pragma unroll
    for (int off = 1; off < 32; off <<= 1) {
        p.x = min(p.x, __shfl_xor(p.x, off));
        p.y = max(p.y, __shfl_xor(p.y, off));
        p.z = min(p.z, __shfl_xor(p.z, off));
        p.w = max(p.w, __shfl_xor(p.w, off));
    }
    if (p.y < 0) { p.x = 0; p.y = HH - 1; }   // all-false mask => [0, n-1]
    if (p.w < 0) { p.z = 0; p.w = WW - 1; }
    return p;
}

__device__ inline void ld3(const float* __restrict__ p, float* d) {
    d[0] = p[0]; d[1] = p[1]; d[2] = p[2];
}

// 2 CONSECUTIVE px per thread (pair never crosses an output row: 400 is even).
// Block = 320 threads * 2 px = 640 px; 250 blocks per batch exactly, so the
// image base pointer is block-uniform (SGPR) and gathers are sgpr-base +
// 32-bit voffset. Phases: coords -> 8 batched dwordx3 gathers -> blend -> NT store.
__global__ void __launch_bounds__(TPB) resize_kernel(
        const float* __restrict__ img,
        const int4* __restrict__ part,
        float* __restrict__ out) {
    const int t    = threadIdx.x;
    const int b    = blockIdx.x / BLKS_PB;                  // block-uniform
    const int rem  = (blockIdx.x % BLKS_PB) * PXB + t * 2;  // px within batch
    const int lane = t & 63;

    int4 f = fold_bounds(part, b, lane);
    const int minR = f.x, maxR = f.y, minC = f.z, maxC = f.w;

    const int ocol = rem % OUTN;     // even; pair = {ocol, ocol+1} same row
    const int orow = rem / OUTN;

    // row coords (shared by the pair) — matches _axis_coords exactly
    float sizeR = (float)(maxR - minR);
    float srcR  = ((float)orow + 0.5f) * sizeR * (1.0f / OUTN) - 0.5f;
    srcR = fminf(fmaxf(srcR, 0.0f), fmaxf(sizeR - 1.0f, 0.0f));
    int   i0 = (int)floorf(srcR);
    int   i1 = min(i0 + 1, max(maxR - minR - 1, 0));
    float wr = srcR - (float)i0;
    const int ro0 = (minR + i0) * (WW * CC);   // float offsets of the two rows
    const int ro1 = (minR + i1) * (WW * CC);

    // col coords for ocol and ocol+1
    const float sizeC  = (float)(maxC - minC);
    const float hiClip = fmaxf(sizeC - 1.0f, 0.0f);
    const int   jmax   = max(maxC - minC - 1, 0);

    float srcC0 = ((float)ocol + 0.5f) * sizeC * (1.0f / OUTN) - 0.5f;
    srcC0 = fminf(fmaxf(srcC0, 0.0f), hiClip);
    int   j00 = (int)floorf(srcC0);
    int   j01 = min(j00 + 1, jmax);
    float wc0 = srcC0 - (float)j00;
    const int c00 = (minC + j00) * CC, c01 = (minC + j01) * CC;

    float srcC1 = ((float)ocol + 1.5f) * sizeC * (1.0f / OUTN) - 0.5f;
    srcC1 = fminf(fmaxf(srcC1, 0.0f), hiClip);
    int   j10 = (int)floorf(srcC1);
    int   j11 = min(j10 + 1, jmax);
    float wc1 = srcC1 - (float)j10;
    const int c10 = (minC + j10) * CC, c11 = (minC + j11) * CC;

    const float* __restrict__ ib = img + (size_t)b * (HH * WW * CC);  // SGPR base

    // load phase: 8 independent dwordx3 gathers, all issued before any use
    float a00[3], a01[3], a10[3], a11[3];   // pixel 0
    float d00[3], d01[3], d10[3], d11[3];   // pixel 1
    ld3(ib + ro0 + c00, a00);
    ld3(ib + ro0 + c01, a01);
    ld3(ib + ro1 + c00, a10);
    ld3(ib + ro1 + c01, a11);
    ld3(ib + ro0 + c10, d00);
    ld3(ib + ro0 + c11, d01);
    ld3(ib + ro1 + c10, d10);
    ld3(ib + ro1 + c11, d11);

    // blend phase
    float res[6];
    {
        float omc = 1.0f - wc0, omr = 1.0f - wr;
        #pragma unroll
        for (int ch = 0; ch < CC; ++ch) {
            float top = a00[ch] * omc + a01[ch] * wc0;
            float bot = a10[ch] * omc + a11[ch] * wc0;
            res[ch] = top * omr + bot * wr;
        }
        omc = 1.0f - wc1;
        #pragma unroll
        for (int ch = 0; ch < CC; ++ch) {
            float top = d00[ch] * omc + d01[ch] * wc1;
            float bot = d10[ch] * omc + d11[ch] * wc1;
            res[3 + ch] = top * omr + bot * wr;
        }
    }

    // store: 24 contiguous bytes per thread, wave covers 1536 B contiguous
    float* o = out + ((size_t)b * PXPB + (size_t)rem) * CC;
    #pragma unroll
    for (int i = 0; i < 6; ++i)
        __builtin_nontemporal_store(res[i], o + i);
}

extern "C" void kernel_launch(void* const* d_in, const int* in_sizes, int n_in,
                              void* d_out, int out_size, void* d_ws, size_t ws_size,
                              hipStream_t stream) {
    const float* image  = (const float*)d_in[0];
    const float* tensor = (const float*)d_in[1];
    float* out  = (float*)d_out;
    int4*  part = (int4*)d_ws;   // 1024 * 16 B = 16 KB

    hipLaunchKernelGGL(bounds_part_kernel, dim3(BB * CHUNKS_PB), dim3(256), 0, stream,
                       tensor, part);

    hipLaunchKernelGGL(resize_kernel, dim3(BB * BLKS_PB), dim3(TPB), 0, stream,
                       image, part, out);
}

// Round 10
// 39.729 us; speedup vs baseline: 1.2839x; 1.1024x over previous
//
#include <hip/hip_runtime.h>

#define OUTN 400
#define THRESH 0.7f
#define BB 32
#define HH 512
#define WW 512
#define CC 3
#define BIGI 0x7FFFFFFF

#define CHUNKS_PB 32                    // bounds chunks per batch
#define ROWS_PC   (HH / CHUNKS_PB)      // 16 rows per chunk
#define PXPB      (OUTN * OUTN)         // 160000 px per batch
#define TPB       320                   // resize threads per block (5 waves)
#define PXB       (TPB * 2)             // 640 px per block -> 250 blocks/batch exact
#define BLKS_PB   (PXPB / PXB)          // 250
#define NXCD      8
#define RGRID     (BB * BLKS_PB)        // 8000 resize blocks, divisible by 8

typedef float vfloat4 __attribute__((ext_vector_type(4)));

// Per-(batch,chunk) partial bounds. Nontemporal loads: tensor is read-once,
// keep it from evicting the image working set out of L2/L3.
__global__ void __launch_bounds__(256) bounds_part_kernel(
        const float* __restrict__ tensor,
        int4* __restrict__ part) {
    const int task  = blockIdx.x;            // 0..1023
    const int b     = task >> 5;
    const int chunk = task & 31;

    const vfloat4* base = (const vfloat4*)(tensor + (size_t)b * HH * WW
                                                  + (size_t)chunk * ROWS_PC * WW);

    int minR = BIGI, maxR = -1, minC = BIGI, maxC = -1;

    // 2048 float4 per chunk, 256 threads, 8 fully-unrolled iterations
    #pragma unroll
    for (int it = 0; it < 8; ++it) {
        int p = threadIdx.x + it * 256;
        vfloat4 v = __builtin_nontemporal_load(base + p);
        int row  = p >> 7;                 // /128 float4 per row, chunk-relative
        int col0 = (p & 127) * 4;
        int mask = (v.x > THRESH ? 1 : 0) | (v.y > THRESH ? 2 : 0)
                 | (v.z > THRESH ? 4 : 0) | (v.w > THRESH ? 8 : 0);
        if (mask) {
            minR = min(minR, row);
            maxR = max(maxR, row);
            minC = min(minC, col0 + __builtin_ctz(mask));
            maxC = max(maxC, col0 + (31 - __builtin_clz(mask)));
        }
    }

    #pragma unroll
    for (int off = 32; off > 0; off >>= 1) {
        minR = min(minR, __shfl_down(minR, off));
        maxR = max(maxR, __shfl_down(maxR, off));
        minC = min(minC, __shfl_down(minC, off));
        maxC = max(maxC, __shfl_down(maxC, off));
    }

    __shared__ int s[4];
    if (threadIdx.x == 0) { s[0] = BIGI; s[1] = -1; s[2] = BIGI; s[3] = -1; }
    __syncthreads();
    if ((threadIdx.x & 63) == 0) {
        atomicMin(&s[0], minR); atomicMax(&s[1], maxR);
        atomicMin(&s[2], minC); atomicMax(&s[3], maxC);
    }
    __syncthreads();
    if (threadIdx.x == 0) {
        int4 r;
        if (s[1] >= 0) {
            r.x = s[0] + chunk * ROWS_PC;
            r.y = s[1] + chunk * ROWS_PC;
            r.z = s[2];
            r.w = s[3];
        } else {
            r.x = BIGI; r.y = -1; r.z = BIGI; r.w = -1;
        }
        part[task] = r;
    }
}

__device__ inline int4 fold_bounds(const int4* __restrict__ part, int b, int lane) {
    int4 p = part[b * CHUNKS_PB + (lane & 31)];
    #pragma unroll
    for (int off = 1; off < 32; off <<= 1) {
        p.x = min(p.x, __shfl_xor(p.x, off));
        p.y = max(p.y, __shfl_xor(p.y, off));
        p.z = min(p.z, __shfl_xor(p.z, off));
        p.w = max(p.w, __shfl_xor(p.w, off));
    }
    if (p.y < 0) { p.x = 0; p.y = HH - 1; }   // all-false mask => [0, n-1]
    if (p.w < 0) { p.z = 0; p.w = WW - 1; }
    return p;
}

__device__ inline void ld3(const float* __restrict__ p, float* d) {
    d[0] = p[0]; d[1] = p[1]; d[2] = p[2];
}

// 2 consecutive px per thread; 250 blocks/batch exactly. XCD-swizzled so each
// XCD owns 4 complete batches: a batch's 3.1 MB image slice fits that XCD's
// 4 MB L2, converting gather misses (L3 latency) into L2 hits.
__global__ void __launch_bounds__(TPB) resize_kernel(
        const float* __restrict__ img,
        const int4* __restrict__ part,
        float* __restrict__ out) {
    // bijective XCD swizzle (RGRID = 8000 divisible by 8):
    // physical p -> logical L = (p%8)*(RGRID/8) + p/8
    const int logical = (blockIdx.x % NXCD) * (RGRID / NXCD) + blockIdx.x / NXCD;

    const int t    = threadIdx.x;
    const int b    = logical / BLKS_PB;                    // block-uniform
    const int rem  = (logical % BLKS_PB) * PXB + t * 2;    // px within batch
    const int lane = t & 63;

    int4 f = fold_bounds(part, b, lane);
    const int minR = f.x, maxR = f.y, minC = f.z, maxC = f.w;

    const int ocol = rem % OUTN;     // even; pair = {ocol, ocol+1} same row
    const int orow = rem / OUTN;

    // row coords (shared by the pair) — matches _axis_coords exactly
    float sizeR = (float)(maxR - minR);
    float srcR  = ((float)orow + 0.5f) * sizeR * (1.0f / OUTN) - 0.5f;
    srcR = fminf(fmaxf(srcR, 0.0f), fmaxf(sizeR - 1.0f, 0.0f));
    int   i0 = (int)floorf(srcR);
    int   i1 = min(i0 + 1, max(maxR - minR - 1, 0));
    float wr = srcR - (float)i0;
    const int ro0 = (minR + i0) * (WW * CC);   // float offsets of the two rows
    const int ro1 = (minR + i1) * (WW * CC);

    // col coords for ocol and ocol+1
    const float sizeC  = (float)(maxC - minC);
    const float hiClip = fmaxf(sizeC - 1.0f, 0.0f);
    const int   jmax   = max(maxC - minC - 1, 0);

    float srcC0 = ((float)ocol + 0.5f) * sizeC * (1.0f / OUTN) - 0.5f;
    srcC0 = fminf(fmaxf(srcC0, 0.0f), hiClip);
    int   j00 = (int)floorf(srcC0);
    int   j01 = min(j00 + 1, jmax);
    float wc0 = srcC0 - (float)j00;
    const int c00 = (minC + j00) * CC, c01 = (minC + j01) * CC;

    float srcC1 = ((float)ocol + 1.5f) * sizeC * (1.0f / OUTN) - 0.5f;
    srcC1 = fminf(fmaxf(srcC1, 0.0f), hiClip);
    int   j10 = (int)floorf(srcC1);
    int   j11 = min(j10 + 1, jmax);
    float wc1 = srcC1 - (float)j10;
    const int c10 = (minC + j10) * CC, c11 = (minC + j11) * CC;

    const float* __restrict__ ib = img + (size_t)b * (HH * WW * CC);  // SGPR base

    // load phase: 8 independent dwordx3 gathers, all issued before any use
    float a00[3], a01[3], a10[3], a11[3];   // pixel 0
    float d00[3], d01[3], d10[3], d11[3];   // pixel 1
    ld3(ib + ro0 + c00, a00);
    ld3(ib + ro0 + c01, a01);
    ld3(ib + ro1 + c00, a10);
    ld3(ib + ro1 + c01, a11);
    ld3(ib + ro0 + c10, d00);
    ld3(ib + ro0 + c11, d01);
    ld3(ib + ro1 + c10, d10);
    ld3(ib + ro1 + c11, d11);

    // blend phase
    float res[6];
    {
        float omc = 1.0f - wc0, omr = 1.0f - wr;
        #pragma unroll
        for (int ch = 0; ch < CC; ++ch) {
            float top = a00[ch] * omc + a01[ch] * wc0;
            float bot = a10[ch] * omc + a11[ch] * wc0;
            res[ch] = top * omr + bot * wr;
        }
        omc = 1.0f - wc1;
        #pragma unroll
        for (int ch = 0; ch < CC; ++ch) {
            float top = d00[ch] * omc + d01[ch] * wc1;
            float bot = d10[ch] * omc + d11[ch] * wc1;
            res[3 + ch] = top * omr + bot * wr;
        }
    }

    // store: 24 contiguous bytes per thread, wave covers 1536 B contiguous
    float* o = out + ((size_t)b * PXPB + (size_t)rem) * CC;
    #pragma unroll
    for (int i = 0; i < 6; ++i)
        __builtin_nontemporal_store(res[i], o + i);
}

extern "C" void kernel_launch(void* const* d_in, const int* in_sizes, int n_in,
                              void* d_out, int out_size, void* d_ws, size_t ws_size,
                              hipStream_t stream) {
    const float* image  = (const float*)d_in[0];
    const float* tensor = (const float*)d_in[1];
    float* out  = (float*)d_out;
    int4*  part = (int4*)d_ws;   // 1024 * 16 B = 16 KB

    hipLaunchKernelGGL(bounds_part_kernel, dim3(BB * CHUNKS_PB), dim3(256), 0, stream,
                       tensor, part);

    hipLaunchKernelGGL(resize_kernel, dim3(RGRID), dim3(TPB), 0, stream,
                       image, part, out);
}